// Round 1
// baseline (290.532 us; speedup 1.0000x reference)
//
#include <hip/hip_runtime.h>
#include <hip/hip_bf16.h>

#define BB 64
#define TT 512
#define EE 768
#define CC 20
#define MID 256

typedef __attribute__((ext_vector_type(8))) short bf16x8;
typedef __attribute__((ext_vector_type(4))) float f32x4;

__device__ __forceinline__ float rlane(float x, int l) {
  return __int_as_float(__builtin_amdgcn_readlane(__float_as_int(x), l));
}
__device__ __forceinline__ short f2bf(float x) {
  union { __hip_bfloat16 h; short s; } u;
  u.h = __float2bfloat16(x);
  return u.s;
}
__device__ __forceinline__ bf16x8 pack8(float4 a, float4 b) {
  bf16x8 r;
  r[0] = f2bf(a.x); r[1] = f2bf(a.y); r[2] = f2bf(a.z); r[3] = f2bf(a.w);
  r[4] = f2bf(b.x); r[5] = f2bf(b.y); r[6] = f2bf(b.z); r[7] = f2bf(b.w);
  return r;
}

// ---------------- pre-pack fc_w into B-fragment layout (bf16)
__global__ __launch_bounds__(256) void packw_kernel(const float* __restrict__ fc_w,
                                                    short* __restrict__ wfrag) {
  int t = blockIdx.x * 256 + threadIdx.x;  // 0 .. 2*24*64-1
  int lane = t & 63;
  int kc = (t >> 6) % 24;
  int tile = t / (24 * 64);
  int n = tile * 16 + (lane & 15);
  if (n >= CC) n = CC - 1;
  int k0 = kc * 32 + (lane >> 4) * 8;
  const float* src = fc_w + (size_t)n * EE + k0;
  float4 x = *(const float4*)src;
  float4 y = *(const float4*)(src + 4);
  ((bf16x8*)wfrag)[t] = pack8(x, y);
}

// ---------------- emissions: 4 waves/block, 64 tokens/block, W direct from L2.
__global__ __launch_bounds__(256) void emissions_kernel(
    const float* __restrict__ hidden, const short* __restrict__ wfrag,
    const float* __restrict__ fc_b, float* __restrict__ em) {
  const int wave = threadIdx.x >> 6;
  const int lane = threadIdx.x & 63;
  const int token0 = blockIdx.x * 64 + wave * 16;
  const int m = lane & 15, q = lane >> 4;
  const float* hrow = hidden + (size_t)(token0 + m) * EE + q * 8;
  const bf16x8* wp = (const bf16x8*)wfrag;  // 48 KiB, L2-resident broadcast
  f32x4 acc0 = {0.f, 0.f, 0.f, 0.f}, acc1 = {0.f, 0.f, 0.f, 0.f};
#pragma unroll 4
  for (int kb = 0; kb < 24; ++kb) {
    float4 a0 = *(const float4*)(hrow + kb * 32);
    float4 a1 = *(const float4*)(hrow + kb * 32 + 4);
    bf16x8 Ab = pack8(a0, a1);
    bf16x8 w0 = wp[kb * 64 + lane];
    bf16x8 w1 = wp[(24 + kb) * 64 + lane];
    acc0 = __builtin_amdgcn_mfma_f32_16x16x32_bf16(Ab, w0, acc0, 0, 0, 0);
    acc1 = __builtin_amdgcn_mfma_f32_16x16x32_bf16(Ab, w1, acc1, 0, 0, 0);
  }
  const int col = lane & 15;
  const float b0v = fc_b[col];
  const bool has1 = (16 + col < CC);
  const float b1v = has1 ? fc_b[16 + col] : 0.f;
#pragma unroll
  for (int r = 0; r < 4; ++r) {
    int tok = token0 + q * 4 + r;
    em[(size_t)tok * CC + col] = acc0[r] + b0v;
    if (has1) em[(size_t)tok * CC + 16 + col] = acc1[r] + b1v;
  }
}

// ---- named-scalar helpers
#define VDECL(Q) float v##Q = rlane(a, Q) + tv[Q]; int j##Q = Q;
#define MRG(A_, B_) { bool k_ = (v##A_ >= v##B_); v##A_ = k_ ? v##A_ : v##B_; j##A_ = k_ ? j##A_ : j##B_; }
__device__ __forceinline__ void vstep(float a, const float (&tv)[CC], float& vm, int& jm) {
  VDECL(0) VDECL(1) VDECL(2) VDECL(3) VDECL(4) VDECL(5) VDECL(6) VDECL(7)
  VDECL(8) VDECL(9) VDECL(10) VDECL(11) VDECL(12) VDECL(13) VDECL(14)
  VDECL(15) VDECL(16) VDECL(17) VDECL(18) VDECL(19)
  MRG(0, 10) MRG(1, 11) MRG(2, 12) MRG(3, 13) MRG(4, 14)
  MRG(5, 15) MRG(6, 16) MRG(7, 17) MRG(8, 18) MRG(9, 19)
  MRG(0, 5) MRG(1, 6) MRG(2, 7) MRG(3, 8) MRG(4, 9)
  MRG(0, 1) MRG(2, 3)
  MRG(0, 2) MRG(0, 4)
  vm = v0; jm = j0;
}
#define XDECL(Q) float x##Q = rlane(x, Q); int y##Q = Q;
#define MRX(A_, B_) { bool k_ = (x##A_ >= x##B_); x##A_ = k_ ? x##A_ : x##B_; y##A_ = k_ ? y##A_ : y##B_; }
__device__ __forceinline__ int lane_argmax(float x) {
  XDECL(0) XDECL(1) XDECL(2) XDECL(3) XDECL(4) XDECL(5) XDECL(6) XDECL(7)
  XDECL(8) XDECL(9) XDECL(10) XDECL(11) XDECL(12) XDECL(13) XDECL(14)
  XDECL(15) XDECL(16) XDECL(17) XDECL(18) XDECL(19)
  MRX(0, 10) MRX(1, 11) MRX(2, 12) MRX(3, 13) MRX(4, 14)
  MRX(5, 15) MRX(6, 16) MRX(7, 17) MRX(8, 18) MRX(9, 19)
  MRX(0, 5) MRX(1, 6) MRX(2, 7) MRX(3, 8) MRX(4, 9)
  MRX(0, 1) MRX(2, 3)
  MRX(0, 2) MRX(0, 4)
  return y0;
}

__device__ __forceinline__ float fdot(float Es, const float (&ET)[CC]) {
  float s0 = rlane(Es, 0) * ET[0];
  float s1 = rlane(Es, 1) * ET[1];
  float s2 = rlane(Es, 2) * ET[2];
  float s3 = rlane(Es, 3) * ET[3];
  s0 = fmaf(rlane(Es, 4), ET[4], s0);
  s1 = fmaf(rlane(Es, 5), ET[5], s1);
  s2 = fmaf(rlane(Es, 6), ET[6], s2);
  s3 = fmaf(rlane(Es, 7), ET[7], s3);
  s0 = fmaf(rlane(Es, 8), ET[8], s0);
  s1 = fmaf(rlane(Es, 9), ET[9], s1);
  s2 = fmaf(rlane(Es, 10), ET[10], s2);
  s3 = fmaf(rlane(Es, 11), ET[11], s3);
  s0 = fmaf(rlane(Es, 12), ET[12], s0);
  s1 = fmaf(rlane(Es, 13), ET[13], s1);
  s2 = fmaf(rlane(Es, 14), ET[14], s2);
  s3 = fmaf(rlane(Es, 15), ET[15], s3);
  s0 = fmaf(rlane(Es, 16), ET[16], s0);
  s1 = fmaf(rlane(Es, 17), ET[17], s1);
  s2 = fmaf(rlane(Es, 18), ET[18], s2);
  s3 = fmaf(rlane(Es, 19), ET[19], s3);
  return (s0 + s1) + (s2 + s3);
}

#define RENORM(Xs, iev)                                        \
  {                                                            \
    float p_ = rlane(Xs, 0);                                   \
    int e_ = ((__float_as_int(p_) >> 23) & 255) - 127;         \
    Xs *= __int_as_float((127 - e_) << 23);                    \
    iev += e_;                                                 \
  }

// ---------------- CRF halves. quad: 0=fwd-fore 1=fwd-back 2=vit-fore 3=vit-back
// 8-step straight-line blocks: prefetch next 8 em+mask off-chain, exp2 batched,
// renorm once per block, backpointers packed 8B/store in layout [32][CC][8].
__global__ __launch_bounds__(64) void crf_half_kernel(
    const float* __restrict__ em, const int* __restrict__ mask,
    const float* __restrict__ st, const float* __restrict__ en,
    const float* __restrict__ tr,
    float* __restrict__ amw, float* __restrict__ bmw,
    float* __restrict__ avw, float* __restrict__ bvw,
    unsigned char* __restrict__ bpws, unsigned char* __restrict__ fpws) {
  __shared__ __align__(16) float emsh[(MID + 1) * CC];  // fore rows 0..256 / back rows 256..511
  __shared__ int msh[TT];
  const int tid = threadIdx.x;
  const int quad = blockIdx.x >> 6;
  const int b = blockIdx.x & (BB - 1);
  const int back = quad & 1;
  const int cc = tid < CC ? tid : CC - 1;
  const float K = 1.44269504088896340736f;

  {
    const float* base = em + (size_t)b * TT * CC + (back ? MID * CC : 0);
    const float4* src = (const float4*)base;
    float4* dst = (float4*)emsh;
#pragma unroll
    for (int k = 0; k < 21; ++k) {
      int i = tid + k * 64;
      if (i < 1285) dst[i] = src[i];  // back: last 5 are dummy (never read)
    }
#pragma unroll
    for (int k = 0; k < 8; ++k) msh[tid + k * 64] = mask[b * TT + tid + k * 64];
  }
  __syncthreads();

  if (quad == 0) {
    // ===== forward alpha, t=1..MID, linear domain =====
    float ET[CC];
#pragma unroll
    for (int q = 0; q < CC; ++q) ET[q] = __builtin_amdgcn_exp2f(tr[q * CC + cc] * K);
    float r = st[cc] + emsh[cc];
    float base0 = rlane(r, 0);
    float Es = __builtin_amdgcn_exp2f((r - base0) * K);
    float off = base0 * K;
    int ie = 0;
    float eev[8]; int mv[8];
#pragma unroll
    for (int i = 0; i < 8; ++i) {
      eev[i] = __builtin_amdgcn_exp2f(emsh[(1 + i) * CC + cc] * K);
      mv[i] = msh[1 + i];
    }
    for (int j = 0; j < 32; ++j) {
      const int tb = (j < 31) ? 8 * j + 9 : 1;  // clamped dummy prefetch at last block
      float emn[8]; int mn[8];
#pragma unroll
      for (int i = 0; i < 8; ++i) { emn[i] = emsh[(tb + i) * CC + cc]; mn[i] = msh[tb + i]; }
#pragma unroll
      for (int i = 0; i < 8; ++i) {
        float s = fdot(Es, ET) * eev[i];
        Es = mv[i] ? s : Es;
      }
      RENORM(Es, ie)
#pragma unroll
      for (int i = 0; i < 8; ++i) {
        eev[i] = __builtin_amdgcn_exp2f(emn[i] * K);
        mv[i] = mn[i];
      }
    }
    if (tid < CC) amw[b * CC + tid] = off + (float)ie + __builtin_amdgcn_logf(Es);
  } else if (quad == 1) {
    // ===== backward beta, t=T-2..MID, linear domain, mask-reset to en =====
    float ETr[CC];
#pragma unroll
    for (int q = 0; q < CC; ++q) ETr[q] = __builtin_amdgcn_exp2f(tr[cc * CC + q] * K);
    const float ENc = __builtin_amdgcn_exp2f(en[cc] * K);
    float Bs = ENc;
    int ie = 0;
    float ee1 = __builtin_amdgcn_exp2f(emsh[255 * CC + cc] * K);  // exp(em[511])
    int m1 = msh[TT - 1];
    // tail: t = 510..504 (7 steps), renorm at t=504
#pragma unroll
    for (int k = 0; k < 7; ++k) {
      const int t = 510 - k;
      float emn = emsh[(t - 256) * CC + cc];
      int mn = msh[t];
      float G = Bs * ee1;
      float s = fdot(G, ETr);
      Bs = m1 ? s : ENc;
      ie = m1 ? ie : 0;
      ee1 = __builtin_amdgcn_exp2f(emn * K);
      m1 = mn;
    }
    RENORM(Bs, ie)
    float eev[8]; int mv[8];
#pragma unroll
    for (int i = 0; i < 8; ++i) {
      eev[i] = __builtin_amdgcn_exp2f(emsh[(247 - i) * CC + cc] * K);
      mv[i] = msh[503 - i];
    }
    for (int j = 0; j < 31; ++j) {  // t = 503-8j .. 496-8j
      const int rb = (j < 30) ? (239 - 8 * j) : 247;  // next block's rows (dummy at last)
      float emn[8]; int mn[8];
#pragma unroll
      for (int i = 0; i < 8; ++i) { emn[i] = emsh[(rb - i) * CC + cc]; mn[i] = msh[rb + 256 - i]; }
#pragma unroll
      for (int i = 0; i < 8; ++i) {
        float G = Bs * ee1;
        float s = fdot(G, ETr);
        Bs = m1 ? s : ENc;
        ie = m1 ? ie : 0;
        ee1 = eev[i];
        m1 = mv[i];
      }
      RENORM(Bs, ie)
#pragma unroll
      for (int i = 0; i < 8; ++i) {
        eev[i] = __builtin_amdgcn_exp2f(emn[i] * K);
        mv[i] = mn[i];
      }
    }
    if (tid < CC) bmw[b * CC + tid] = (float)ie + __builtin_amdgcn_logf(Bs);
  } else if (quad == 2) {
    // ===== viterbi fore, t=1..MID, bp packed [32][CC][8] =====
    float tv[CC];
#pragma unroll
    for (int q = 0; q < CC; ++q) tv[q] = tr[q * CC + cc];
    float a = st[cc] + emsh[cc];
    unsigned char* bp = bpws + (size_t)b * MID * CC;
    float emv[8]; int mv[8];
#pragma unroll
    for (int i = 0; i < 8; ++i) { emv[i] = emsh[(1 + i) * CC + cc]; mv[i] = msh[1 + i]; }
    for (int j = 0; j < 32; ++j) {
      const int tb = (j < 31) ? 8 * j + 9 : 1;
      float emn[8]; int mn[8];
#pragma unroll
      for (int i = 0; i < 8; ++i) { emn[i] = emsh[(tb + i) * CC + cc]; mn[i] = msh[tb + i]; }
      unsigned lo = 0, hi = 0;
#pragma unroll
      for (int i = 0; i < 8; ++i) {
        float vm; int jm;
        vstep(a, tv, vm, jm);
        if (i < 4) lo |= (unsigned)jm << (8 * i); else hi |= (unsigned)jm << (8 * (i - 4));
        float au = vm + emv[i];
        a = mv[i] ? au : a;
      }
      if (tid < CC) {
        int2 w; w.x = (int)lo; w.y = (int)hi;
        *(int2*)(bp + j * 160 + tid * 8) = w;
      }
#pragma unroll
      for (int i = 0; i < 8; ++i) { emv[i] = emn[i]; mv[i] = mn[i]; }
    }
    if (tid < CC) avw[b * CC + tid] = a;
  } else {
    // ===== viterbi back, t=T-2..MID, fp packed [32][CC][8] =====
    float tv[CC];
#pragma unroll
    for (int q = 0; q < CC; ++q) tv[q] = tr[cc * CC + q];
    const float ENv = en[cc];
    float Vb = ENv;
    float em1 = emsh[255 * CC + cc];  // em[511]
    int m1 = msh[TT - 1];
    unsigned char* fp = fpws + (size_t)b * MID * CC;
    // tail: t = 510..504 -> idx 254..248, blk 31, bytes 6..0 (byte 7 unused)
    {
      unsigned lo = 0, hi = 0;
#pragma unroll
      for (int k = 0; k < 7; ++k) {
        const int t = 510 - k;
        float emn = emsh[(t - 256) * CC + cc];
        int mn = msh[t];
        float av = Vb + em1;
        float vm; int jm;
        vstep(av, tv, vm, jm);
        const int ib = 6 - k;
        if (ib < 4) lo |= (unsigned)jm << (8 * ib); else hi |= (unsigned)jm << (8 * (ib - 4));
        Vb = m1 ? vm : ENv;
        em1 = emn;
        m1 = mn;
      }
      if (tid < CC) {
        int2 w; w.x = (int)lo; w.y = (int)hi;
        *(int2*)(fp + 31 * 160 + tid * 8) = w;
      }
    }
    float emv[8]; int mv[8];
#pragma unroll
    for (int i = 0; i < 8; ++i) { emv[i] = emsh[(247 - i) * CC + cc]; mv[i] = msh[503 - i]; }
    for (int j = 0; j < 31; ++j) {  // t = 503-8j .. 496-8j -> blk 30-j, bytes 7..0
      const int rb = (j < 30) ? (239 - 8 * j) : 247;
      float emn[8]; int mn[8];
#pragma unroll
      for (int i = 0; i < 8; ++i) { emn[i] = emsh[(rb - i) * CC + cc]; mn[i] = msh[rb + 256 - i]; }
      unsigned lo = 0, hi = 0;
#pragma unroll
      for (int i = 0; i < 8; ++i) {
        float av = Vb + em1;
        float vm; int jm;
        vstep(av, tv, vm, jm);
        const int ib = 7 - i;
        if (ib < 4) lo |= (unsigned)jm << (8 * ib); else hi |= (unsigned)jm << (8 * (ib - 4));
        Vb = m1 ? vm : ENv;
        em1 = emv[i];
        m1 = mv[i];
      }
      if (tid < CC) {
        int2 w; w.x = (int)lo; w.y = (int)hi;
        *(int2*)(fp + (30 - j) * 160 + tid * 8) = w;
      }
#pragma unroll
      for (int i = 0; i < 8; ++i) { emv[i] = emn[i]; mv[i] = mn[i]; }
    }
    if (tid < CC) bvw[b * CC + tid] = Vb;
  }
}

// ---------------- finish: join halves, backtrace both ways, numerator, llh
__global__ __launch_bounds__(64) void finish_kernel(
    const float* __restrict__ em, const int* __restrict__ mask,
    const int* __restrict__ labels, const float* __restrict__ st,
    const float* __restrict__ en, const float* __restrict__ tr,
    const float* __restrict__ amw, const float* __restrict__ bmw,
    const float* __restrict__ avw, const float* __restrict__ bvw,
    const unsigned char* __restrict__ bpws, const unsigned char* __restrict__ fpws,
    float* __restrict__ llh, float* __restrict__ out) {
  __shared__ __align__(16) unsigned char hl[2 * MID * CC];  // 10240
  const int b = blockIdx.x;
  const int tid = threadIdx.x;
  const int cc = tid < CC ? tid : CC - 1;
  const float LN2 = 0.69314718055994530942f;
  {
    const int4* bsrc = (const int4*)(bpws + (size_t)b * MID * CC);
    const int4* fsrc = (const int4*)(fpws + (size_t)b * MID * CC);
    int4* dst = (int4*)hl;
#pragma unroll
    for (int k = 0; k < 5; ++k) {
      int i = tid + k * 64;
      dst[i] = bsrc[i];
      dst[320 + i] = fsrc[i];
    }
  }
  __syncthreads();

  // --- viterbi join + dual backtrace ---
  int cstar = lane_argmax(avw[b * CC + cc] + bvw[b * CC + cc]);
  float* ob = out + 1 + (size_t)b * TT;
  if (tid == 0) ob[MID] = (float)(cstar + 1);
  // backward: s = 255..0, tag_s = bp[s][tag_{s+1}]; layout [s>>3][cc][s&7]
  {
    int tag = cstar;
    int s = MID - 1;
    while (s >= 7) {
      const unsigned char* hb = hl + (s >> 3) * 160 + cc * 8;
      int2 w = *(const int2*)hb;
      int g0 = (w.y >> 24) & 255, g1 = (w.y >> 16) & 255, g2 = (w.y >> 8) & 255, g3 = w.y & 255;
      int g4 = (w.x >> 24) & 255, g5 = (w.x >> 16) & 255, g6 = (w.x >> 8) & 255, g7 = w.x & 255;
      tag = __builtin_amdgcn_readlane(g0, tag); float f0 = (float)(tag + 1);
      tag = __builtin_amdgcn_readlane(g1, tag); float f1 = (float)(tag + 1);
      tag = __builtin_amdgcn_readlane(g2, tag); float f2 = (float)(tag + 1);
      tag = __builtin_amdgcn_readlane(g3, tag); float f3 = (float)(tag + 1);
      tag = __builtin_amdgcn_readlane(g4, tag); float f4 = (float)(tag + 1);
      tag = __builtin_amdgcn_readlane(g5, tag); float f5 = (float)(tag + 1);
      tag = __builtin_amdgcn_readlane(g6, tag); float f6 = (float)(tag + 1);
      tag = __builtin_amdgcn_readlane(g7, tag); float f7 = (float)(tag + 1);
      if (tid == 0) {
        ob[s - 0] = f0; ob[s - 1] = f1; ob[s - 2] = f2; ob[s - 3] = f3;
        ob[s - 4] = f4; ob[s - 5] = f5; ob[s - 6] = f6; ob[s - 7] = f7;
      }
      s -= 8;
    }
  }
  // forward: u = 0..254, tag_{t+1} = fp[u][tag_t]; layout [u>>3][cc][u&7]
  {
    int tag = cstar;
    int u = 0;
    while (u + 7 <= MID - 2) {
      const unsigned char* hb = hl + MID * CC + (u >> 3) * 160 + cc * 8;
      int2 w = *(const int2*)hb;
      int g0 = w.x & 255, g1 = (w.x >> 8) & 255, g2 = (w.x >> 16) & 255, g3 = (w.x >> 24) & 255;
      int g4 = w.y & 255, g5 = (w.y >> 8) & 255, g6 = (w.y >> 16) & 255, g7 = (w.y >> 24) & 255;
      tag = __builtin_amdgcn_readlane(g0, tag); float f0 = (float)(tag + 1);
      tag = __builtin_amdgcn_readlane(g1, tag); float f1 = (float)(tag + 1);
      tag = __builtin_amdgcn_readlane(g2, tag); float f2 = (float)(tag + 1);
      tag = __builtin_amdgcn_readlane(g3, tag); float f3 = (float)(tag + 1);
      tag = __builtin_amdgcn_readlane(g4, tag); float f4 = (float)(tag + 1);
      tag = __builtin_amdgcn_readlane(g5, tag); float f5 = (float)(tag + 1);
      tag = __builtin_amdgcn_readlane(g6, tag); float f6 = (float)(tag + 1);
      tag = __builtin_amdgcn_readlane(g7, tag); float f7 = (float)(tag + 1);
      if (tid == 0) {
        ob[MID + 1 + u + 0] = f0; ob[MID + 1 + u + 1] = f1;
        ob[MID + 1 + u + 2] = f2; ob[MID + 1 + u + 3] = f3;
        ob[MID + 1 + u + 4] = f4; ob[MID + 1 + u + 5] = f5;
        ob[MID + 1 + u + 6] = f6; ob[MID + 1 + u + 7] = f7;
      }
      u += 8;
    }
    while (u <= MID - 2) {
      int g = hl[MID * CC + (u >> 3) * 160 + cc * 8 + (u & 7)];
      tag = __builtin_amdgcn_readlane(g, tag);
      if (tid == 0) ob[MID + 1 + u] = (float)(tag + 1);
      ++u;
    }
  }

  // --- norm = LN2 * lse2(am + bm) ---
  float zn = amw[b * CC + cc] + bmw[b * CC + cc];
  float M = zn;
#pragma unroll
  for (int o = 32; o >= 1; o >>= 1) M = fmaxf(M, __shfl_xor(M, o));
  float sE = (tid < CC) ? __builtin_amdgcn_exp2f(zn - M) : 0.f;
#pragma unroll
  for (int o = 32; o >= 1; o >>= 1) sE += __shfl_xor(sE, o);
  float norm = LN2 * (M + __builtin_amdgcn_logf(sE));

  // --- numerator ---
  const int* lab = labels + b * TT;
  const float* emg = em + (size_t)b * TT * CC;
  float sc = 0.f;
  int msum = 0;
  for (int k = tid; k < TT; k += 64) {
    int mk = mask[b * TT + k];
    msum += mk;
    if (k >= 1) {
      int tg = lab[k], tp = lab[k - 1];
      sc += (tr[tp * CC + tg] + emg[k * CC + tg]) * (float)mk;
    }
  }
#pragma unroll
  for (int o = 32; o >= 1; o >>= 1) {
    sc += __shfl_xor(sc, o);
    msum += __shfl_xor(msum, o);
  }
  int seq_end = msum - 1;
  int t0 = lab[0], tl = lab[seq_end];
  float score = sc + st[t0] + emg[t0] + en[tl];
  if (tid == 0) llh[b] = score - norm;
}

__global__ __launch_bounds__(64) void loss_kernel(const float* __restrict__ llh,
                                                  float* __restrict__ out) {
  float v = llh[threadIdx.x];
#pragma unroll
  for (int o = 32; o >= 1; o >>= 1) v += __shfl_xor(v, o);
  if (threadIdx.x == 0) out[0] = -(v * (1.0f / 64.0f));
}

extern "C" void kernel_launch(void* const* d_in, const int* in_sizes, int n_in,
                              void* d_out, int out_size, void* d_ws, size_t ws_size,
                              hipStream_t stream) {
  const float* hidden = (const float*)d_in[0];
  const int* amask = (const int*)d_in[1];
  const int* labels = (const int*)d_in[2];
  const float* fc_w = (const float*)d_in[3];
  const float* fc_b = (const float*)d_in[4];
  const float* st = (const float*)d_in[5];
  const float* en = (const float*)d_in[6];
  const float* tr = (const float*)d_in[7];

  float* emws = (float*)d_ws;                          // 655360 floats
  float* llh = emws + (size_t)BB * TT * CC;            // 64
  short* wfrag = (short*)(llh + 64);                   // 24576 shorts
  float* amw = (float*)(wfrag + 24576);                // 1280
  float* bmw = amw + BB * CC;
  float* avw = bmw + BB * CC;
  float* bvw = avw + BB * CC;
  unsigned char* bpws = (unsigned char*)(bvw + BB * CC);  // 327680 B (16B aligned)
  unsigned char* fpws = bpws + (size_t)BB * MID * CC;     // 327680 B
  float* out = (float*)d_out;

  packw_kernel<<<(2 * 24 * 64) / 256, 256, 0, stream>>>(fc_w, wfrag);
  emissions_kernel<<<(BB * TT) / 64, 256, 0, stream>>>(hidden, wfrag, fc_b, emws);
  crf_half_kernel<<<4 * BB, 64, 0, stream>>>(emws, amask, st, en, tr,
                                             amw, bmw, avw, bvw, bpws, fpws);
  finish_kernel<<<BB, 64, 0, stream>>>(emws, amask, labels, st, en, tr,
                                       amw, bmw, avw, bvw, bpws, fpws, llh, out);
  loss_kernel<<<1, 64, 0, stream>>>(llh, out);
}

// Round 2
// 250.547 us; speedup vs baseline: 1.1596x; 1.1596x over previous
//
#include <hip/hip_runtime.h>
#include <hip/hip_bf16.h>

#define BB 64
#define TT 512
#define EE 768
#define CC 20
#define MID 256

typedef __attribute__((ext_vector_type(8))) short bf16x8;
typedef __attribute__((ext_vector_type(4))) float f32x4;

__device__ __forceinline__ float rlane(float x, int l) {
  return __int_as_float(__builtin_amdgcn_readlane(__float_as_int(x), l));
}
__device__ __forceinline__ short f2bf(float x) {
  union { __hip_bfloat16 h; short s; } u;
  u.h = __float2bfloat16(x);
  return u.s;
}
__device__ __forceinline__ bf16x8 pack8(float4 a, float4 b) {
  bf16x8 r;
  r[0] = f2bf(a.x); r[1] = f2bf(a.y); r[2] = f2bf(a.z); r[3] = f2bf(a.w);
  r[4] = f2bf(b.x); r[5] = f2bf(b.y); r[6] = f2bf(b.z); r[7] = f2bf(b.w);
  return r;
}

// ---------------- pre-pack fc_w into B-fragment layout (bf16)
__global__ __launch_bounds__(256) void packw_kernel(const float* __restrict__ fc_w,
                                                    short* __restrict__ wfrag) {
  int t = blockIdx.x * 256 + threadIdx.x;  // 0 .. 2*24*64-1
  int lane = t & 63;
  int kc = (t >> 6) % 24;
  int tile = t / (24 * 64);
  int n = tile * 16 + (lane & 15);
  if (n >= CC) n = CC - 1;
  int k0 = kc * 32 + (lane >> 4) * 8;
  const float* src = fc_w + (size_t)n * EE + k0;
  float4 x = *(const float4*)src;
  float4 y = *(const float4*)(src + 4);
  ((bf16x8*)wfrag)[t] = pack8(x, y);
}

// ---------------- emissions: 4 waves/block, 64 tokens/block, W direct from L2.
__global__ __launch_bounds__(256) void emissions_kernel(
    const float* __restrict__ hidden, const short* __restrict__ wfrag,
    const float* __restrict__ fc_b, float* __restrict__ em) {
  const int wave = threadIdx.x >> 6;
  const int lane = threadIdx.x & 63;
  const int token0 = blockIdx.x * 64 + wave * 16;
  const int m = lane & 15, q = lane >> 4;
  const float* hrow = hidden + (size_t)(token0 + m) * EE + q * 8;
  const bf16x8* wp = (const bf16x8*)wfrag;  // 48 KiB, L2-resident broadcast
  f32x4 acc0 = {0.f, 0.f, 0.f, 0.f}, acc1 = {0.f, 0.f, 0.f, 0.f};
#pragma unroll 4
  for (int kb = 0; kb < 24; ++kb) {
    float4 a0 = *(const float4*)(hrow + kb * 32);
    float4 a1 = *(const float4*)(hrow + kb * 32 + 4);
    bf16x8 Ab = pack8(a0, a1);
    bf16x8 w0 = wp[kb * 64 + lane];
    bf16x8 w1 = wp[(24 + kb) * 64 + lane];
    acc0 = __builtin_amdgcn_mfma_f32_16x16x32_bf16(Ab, w0, acc0, 0, 0, 0);
    acc1 = __builtin_amdgcn_mfma_f32_16x16x32_bf16(Ab, w1, acc1, 0, 0, 0);
  }
  const int col = lane & 15;
  const float b0v = fc_b[col];
  const bool has1 = (16 + col < CC);
  const float b1v = has1 ? fc_b[16 + col] : 0.f;
#pragma unroll
  for (int r = 0; r < 4; ++r) {
    int tok = token0 + q * 4 + r;
    em[(size_t)tok * CC + col] = acc0[r] + b0v;
    if (has1) em[(size_t)tok * CC + 16 + col] = acc1[r] + b1v;
  }
}

// ---- packed-u32 argmax vstep: values must be strictly positive floats.
// key = (asuint(v) & ~31) | j ; uint order == float order for positive floats.
// No v_cmp/vcc anywhere -> no VCC serialization in the merge tree.
__device__ __forceinline__ unsigned umax_(unsigned a, unsigned b) { return a > b ? a : b; }
__device__ __forceinline__ unsigned umax3_(unsigned a, unsigned b, unsigned c) {
  return umax_(umax_(a, b), c);
}
#define PDECL(Q) unsigned p##Q = (__float_as_uint(rlane(a, Q) + tv[Q]) & 0xFFFFFFE0u) | Q##u;
__device__ __forceinline__ void vstep(float a, const float (&tv)[CC], float& vm, int& jm) {
  PDECL(0) PDECL(1) PDECL(2) PDECL(3) PDECL(4) PDECL(5) PDECL(6) PDECL(7)
  PDECL(8) PDECL(9) PDECL(10) PDECL(11) PDECL(12) PDECL(13) PDECL(14)
  PDECL(15) PDECL(16) PDECL(17) PDECL(18) PDECL(19)
  unsigned m0 = umax3_(p0, p1, p2);
  unsigned m1 = umax3_(p3, p4, p5);
  unsigned m2 = umax3_(p6, p7, p8);
  unsigned m3 = umax3_(p9, p10, p11);
  unsigned m4 = umax3_(p12, p13, p14);
  unsigned m5 = umax3_(p15, p16, p17);
  unsigned n0 = umax3_(m0, m1, m2);
  unsigned n1 = umax3_(m3, m4, m5);
  unsigned n2 = umax_(p18, p19);
  unsigned r = umax3_(n0, n1, n2);
  vm = __uint_as_float(r & 0xFFFFFFE0u);
  jm = (int)(r & 31u);
}

#define XDECL(Q) float x##Q = rlane(x, Q); int y##Q = Q;
#define MRX(A_, B_) { bool k_ = (x##A_ >= x##B_); x##A_ = k_ ? x##A_ : x##B_; y##A_ = k_ ? y##A_ : y##B_; }
__device__ __forceinline__ int lane_argmax(float x) {
  XDECL(0) XDECL(1) XDECL(2) XDECL(3) XDECL(4) XDECL(5) XDECL(6) XDECL(7)
  XDECL(8) XDECL(9) XDECL(10) XDECL(11) XDECL(12) XDECL(13) XDECL(14)
  XDECL(15) XDECL(16) XDECL(17) XDECL(18) XDECL(19)
  MRX(0, 10) MRX(1, 11) MRX(2, 12) MRX(3, 13) MRX(4, 14)
  MRX(5, 15) MRX(6, 16) MRX(7, 17) MRX(8, 18) MRX(9, 19)
  MRX(0, 5) MRX(1, 6) MRX(2, 7) MRX(3, 8) MRX(4, 9)
  MRX(0, 1) MRX(2, 3)
  MRX(0, 2) MRX(0, 4)
  return y0;
}

__device__ __forceinline__ float fdot(float Es, const float (&ET)[CC]) {
  float s0 = rlane(Es, 0) * ET[0];
  float s1 = rlane(Es, 1) * ET[1];
  float s2 = rlane(Es, 2) * ET[2];
  float s3 = rlane(Es, 3) * ET[3];
  s0 = fmaf(rlane(Es, 4), ET[4], s0);
  s1 = fmaf(rlane(Es, 5), ET[5], s1);
  s2 = fmaf(rlane(Es, 6), ET[6], s2);
  s3 = fmaf(rlane(Es, 7), ET[7], s3);
  s0 = fmaf(rlane(Es, 8), ET[8], s0);
  s1 = fmaf(rlane(Es, 9), ET[9], s1);
  s2 = fmaf(rlane(Es, 10), ET[10], s2);
  s3 = fmaf(rlane(Es, 11), ET[11], s3);
  s0 = fmaf(rlane(Es, 12), ET[12], s0);
  s1 = fmaf(rlane(Es, 13), ET[13], s1);
  s2 = fmaf(rlane(Es, 14), ET[14], s2);
  s3 = fmaf(rlane(Es, 15), ET[15], s3);
  s0 = fmaf(rlane(Es, 16), ET[16], s0);
  s1 = fmaf(rlane(Es, 17), ET[17], s1);
  s2 = fmaf(rlane(Es, 18), ET[18], s2);
  s3 = fmaf(rlane(Es, 19), ET[19], s3);
  return (s0 + s1) + (s2 + s3);
}

// ---------------- CRF halves. quad: 0=fwd-fore 1=fwd-back 2=vit-fore 3=vit-back
__global__ __launch_bounds__(64) void crf_half_kernel(
    const float* __restrict__ em, const int* __restrict__ mask,
    const float* __restrict__ st, const float* __restrict__ en,
    const float* __restrict__ tr,
    float* __restrict__ amw, float* __restrict__ bmw,
    float* __restrict__ avw, float* __restrict__ bvw,
    unsigned char* __restrict__ bpws, unsigned char* __restrict__ fpws) {
  __shared__ float emsh[(MID + 1) * CC];  // fore: rows 0..256; back: rows 256..511
  __shared__ int msh[TT];
  const int tid = threadIdx.x;
  const int quad = blockIdx.x >> 6;
  const int b = blockIdx.x & (BB - 1);
  const int back = quad & 1;
  const int cc = tid < CC ? tid : CC - 1;
  const float K = 1.44269504088896340736f;
  const float BIAS = 64.0f;  // viterbi states kept in (BIAS-32, BIAS+32): strictly positive

  {
    const float* base = em + (size_t)b * TT * CC + (back ? MID * CC : 0);
    int nf4 = back ? (MID * CC / 4) : ((MID + 1) * CC / 4);  // 1280 or 1285
    const float4* src = (const float4*)base;
    float4* dst = (float4*)emsh;
    for (int i = tid; i < nf4; i += 64) dst[i] = src[i];
    for (int i = tid; i < TT; i += 64) msh[i] = mask[b * TT + i];
  }
  __syncthreads();

  if (quad == 0) {
    // ===== forward alpha, t=0..MID, linear domain =====
    float ET[CC];
#pragma unroll
    for (int q = 0; q < CC; ++q) ET[q] = __builtin_amdgcn_exp2f(tr[q * CC + cc] * K);
    float r = st[cc] + emsh[cc];
    float base0 = rlane(r, 0);
    float Es = __builtin_amdgcn_exp2f((r - base0) * K);
    float off = base0 * K;
    int ie = 0;
    float emc = emsh[CC + cc];
    int mcur = msh[1];
    float eec = __builtin_amdgcn_exp2f(emc * K);
    for (int t = 1; t <= MID; ++t) {
      int tn = (t < MID) ? t + 1 : t;
      float emn = emsh[tn * CC + cc];
      int mn = msh[tn];
      float s = fdot(Es, ET) * eec;
      Es = mcur ? s : Es;
      if ((t & 7) == 0) {
        float p = rlane(Es, 0);
        int e = ((__float_as_int(p) >> 23) & 255) - 127;
        Es *= __int_as_float((127 - e) << 23);
        ie += e;
      }
      eec = __builtin_amdgcn_exp2f(emn * K);
      mcur = mn;
    }
    if (tid < CC) amw[b * CC + tid] = off + (float)ie + __builtin_amdgcn_logf(Es);
  } else if (quad == 1) {
    // ===== backward beta, t=T-2..MID, linear domain, mask-reset to en =====
    float ETr[CC];
#pragma unroll
    for (int q = 0; q < CC; ++q) ETr[q] = __builtin_amdgcn_exp2f(tr[cc * CC + q] * K);
    const float ENc = __builtin_amdgcn_exp2f(en[cc] * K);
    float Bs = ENc;
    int ie = 0;
    float em1 = emsh[(TT - 1 - MID) * CC + cc];  // em_{511}
    int m1 = msh[TT - 1];
    float ee1 = __builtin_amdgcn_exp2f(em1 * K);
    for (int t = TT - 2; t >= MID; --t) {
      float emn = emsh[(t - MID) * CC + cc];  // em_t (next iter's em_{t+1})
      int mn = msh[t];
      float G = Bs * ee1;
      float s = fdot(G, ETr);
      Bs = m1 ? s : ENc;
      ie = m1 ? ie : 0;
      if ((t & 7) == 0) {
        float p = rlane(Bs, 0);
        int e = ((__float_as_int(p) >> 23) & 255) - 127;
        Bs *= __int_as_float((127 - e) << 23);
        ie += e;
      }
      ee1 = __builtin_amdgcn_exp2f(emn * K);
      m1 = mn;
    }
    if (tid < CC) bmw[b * CC + tid] = (float)ie + __builtin_amdgcn_logf(Bs);
  } else if (quad == 2) {
    // ===== viterbi fore, t=1..MID, biased-positive state, packed-u32 argmax =====
    float tv[CC];
#pragma unroll
    for (int q = 0; q < CC; ++q) tv[q] = tr[q * CC + cc];
    float a = st[cc] + emsh[cc] + BIAS;
    float emc = emsh[CC + cc];
    int mcur = msh[1];
    unsigned char* bp = bpws + (size_t)b * MID * CC;
    for (int t = 1; t <= MID; ++t) {
      int tn = (t < MID) ? t + 1 : t;
      float emn = emsh[tn * CC + cc];
      int mn = msh[tn];
      float vm;
      int jm;
      vstep(a, tv, vm, jm);
      if (tid < CC) bp[(t - 1) * CC + tid] = (unsigned char)jm;
      float au = vm + emc;
      a = mcur ? au : a;
      if ((t & 7) == 0) a += (BIAS - rlane(a, 0));  // uniform shift: argmax-invariant
      emc = emn;
      mcur = mn;
    }
    if (tid < CC) avw[b * CC + tid] = a;
  } else {
    // ===== viterbi back, t=T-2..MID, biased-positive state, packed-u32 argmax =====
    float tv[CC];
#pragma unroll
    for (int q = 0; q < CC; ++q) tv[q] = tr[cc * CC + q];  // row of tr
    const float ENv = en[cc] + BIAS;
    float Vb = ENv;
    float em1 = emsh[(TT - 1 - MID) * CC + cc];
    int m1 = msh[TT - 1];
    unsigned char* fp = fpws + (size_t)b * MID * CC;
    for (int t = TT - 2; t >= MID; --t) {
      float emn = emsh[(t - MID) * CC + cc];
      int mn = msh[t];
      float a = Vb + em1;  // broadcast operand (positive)
      float vm;
      int jm;
      vstep(a, tv, vm, jm);
      if (tid < CC) fp[(t - MID) * CC + tid] = (unsigned char)jm;
      Vb = m1 ? vm : ENv;
      if ((t & 7) == 0) Vb += (BIAS - rlane(Vb, 0));  // uniform shift: argmax-invariant
      em1 = emn;
      m1 = mn;
    }
    if (tid < CC) bvw[b * CC + tid] = Vb;
  }
}

// ---------------- finish: join halves, backtrace both ways, numerator, llh
__global__ __launch_bounds__(64) void finish_kernel(
    const float* __restrict__ em, const int* __restrict__ mask,
    const int* __restrict__ labels, const float* __restrict__ st,
    const float* __restrict__ en, const float* __restrict__ tr,
    const float* __restrict__ amw, const float* __restrict__ bmw,
    const float* __restrict__ avw, const float* __restrict__ bvw,
    const unsigned char* __restrict__ bpws, const unsigned char* __restrict__ fpws,
    float* __restrict__ llh, float* __restrict__ out) {
  __shared__ unsigned char hl[2 * MID * CC];  // 10240
  const int b = blockIdx.x;
  const int tid = threadIdx.x;
  const int cc = tid < CC ? tid : CC - 1;
  const float LN2 = 0.69314718055994530942f;
  {
    const int4* bsrc = (const int4*)(bpws + (size_t)b * MID * CC);
    const int4* fsrc = (const int4*)(fpws + (size_t)b * MID * CC);
    int4* dst = (int4*)hl;
    for (int i = tid; i < 320; i += 64) {
      dst[i] = bsrc[i];
      dst[320 + i] = fsrc[i];
    }
  }
  __syncthreads();

  // --- viterbi join + dual backtrace ---
  int cstar = lane_argmax(avw[b * CC + cc] + bvw[b * CC + cc]);
  float* ob = out + 1 + (size_t)b * TT;
  if (tid == 0) ob[MID] = (float)(cstar + 1);
  // backward: s = 255..0, tag_s = bp[s][tag_{s+1}] ; 256 = 32*8 exact
  {
    int tag = cstar;
    int s = MID - 1;
    while (s >= 7) {
      int g0 = hl[(s - 0) * CC + cc];
      int g1 = hl[(s - 1) * CC + cc];
      int g2 = hl[(s - 2) * CC + cc];
      int g3 = hl[(s - 3) * CC + cc];
      int g4 = hl[(s - 4) * CC + cc];
      int g5 = hl[(s - 5) * CC + cc];
      int g6 = hl[(s - 6) * CC + cc];
      int g7 = hl[(s - 7) * CC + cc];
      tag = __builtin_amdgcn_readlane(g0, tag); float f0 = (float)(tag + 1);
      tag = __builtin_amdgcn_readlane(g1, tag); float f1 = (float)(tag + 1);
      tag = __builtin_amdgcn_readlane(g2, tag); float f2 = (float)(tag + 1);
      tag = __builtin_amdgcn_readlane(g3, tag); float f3 = (float)(tag + 1);
      tag = __builtin_amdgcn_readlane(g4, tag); float f4 = (float)(tag + 1);
      tag = __builtin_amdgcn_readlane(g5, tag); float f5 = (float)(tag + 1);
      tag = __builtin_amdgcn_readlane(g6, tag); float f6 = (float)(tag + 1);
      tag = __builtin_amdgcn_readlane(g7, tag); float f7 = (float)(tag + 1);
      if (tid == 0) {
        ob[s - 0] = f0; ob[s - 1] = f1; ob[s - 2] = f2; ob[s - 3] = f3;
        ob[s - 4] = f4; ob[s - 5] = f5; ob[s - 6] = f6; ob[s - 7] = f7;
      }
      s -= 8;
    }
  }
  // forward: u = 0..254, tag_{t+1} = fp[u][tag_t], t = MID+u
  {
    int tag = cstar;
    int u = 0;
    while (u + 7 <= MID - 2) {
      int g0 = hl[MID * CC + (u + 0) * CC + cc];
      int g1 = hl[MID * CC + (u + 1) * CC + cc];
      int g2 = hl[MID * CC + (u + 2) * CC + cc];
      int g3 = hl[MID * CC + (u + 3) * CC + cc];
      int g4 = hl[MID * CC + (u + 4) * CC + cc];
      int g5 = hl[MID * CC + (u + 5) * CC + cc];
      int g6 = hl[MID * CC + (u + 6) * CC + cc];
      int g7 = hl[MID * CC + (u + 7) * CC + cc];
      tag = __builtin_amdgcn_readlane(g0, tag); float f0 = (float)(tag + 1);
      tag = __builtin_amdgcn_readlane(g1, tag); float f1 = (float)(tag + 1);
      tag = __builtin_amdgcn_readlane(g2, tag); float f2 = (float)(tag + 1);
      tag = __builtin_amdgcn_readlane(g3, tag); float f3 = (float)(tag + 1);
      tag = __builtin_amdgcn_readlane(g4, tag); float f4 = (float)(tag + 1);
      tag = __builtin_amdgcn_readlane(g5, tag); float f5 = (float)(tag + 1);
      tag = __builtin_amdgcn_readlane(g6, tag); float f6 = (float)(tag + 1);
      tag = __builtin_amdgcn_readlane(g7, tag); float f7 = (float)(tag + 1);
      if (tid == 0) {
        ob[MID + 1 + u + 0] = f0; ob[MID + 1 + u + 1] = f1;
        ob[MID + 1 + u + 2] = f2; ob[MID + 1 + u + 3] = f3;
        ob[MID + 1 + u + 4] = f4; ob[MID + 1 + u + 5] = f5;
        ob[MID + 1 + u + 6] = f6; ob[MID + 1 + u + 7] = f7;
      }
      u += 8;
    }
    while (u <= MID - 2) {
      int g = hl[MID * CC + u * CC + cc];
      tag = __builtin_amdgcn_readlane(g, tag);
      if (tid == 0) ob[MID + 1 + u] = (float)(tag + 1);
      ++u;
    }
  }

  // --- norm = LN2 * lse2(am + bm) ---
  float zn = amw[b * CC + cc] + bmw[b * CC + cc];
  float M = zn;
#pragma unroll
  for (int o = 32; o >= 1; o >>= 1) M = fmaxf(M, __shfl_xor(M, o));
  float sE = (tid < CC) ? __builtin_amdgcn_exp2f(zn - M) : 0.f;
#pragma unroll
  for (int o = 32; o >= 1; o >>= 1) sE += __shfl_xor(sE, o);
  float norm = LN2 * (M + __builtin_amdgcn_logf(sE));

  // --- numerator ---
  const int* lab = labels + b * TT;
  const float* emg = em + (size_t)b * TT * CC;
  float sc = 0.f;
  int msum = 0;
  for (int k = tid; k < TT; k += 64) {
    int mk = mask[b * TT + k];
    msum += mk;
    if (k >= 1) {
      int tg = lab[k], tp = lab[k - 1];
      sc += (tr[tp * CC + tg] + emg[k * CC + tg]) * (float)mk;
    }
  }
#pragma unroll
  for (int o = 32; o >= 1; o >>= 1) {
    sc += __shfl_xor(sc, o);
    msum += __shfl_xor(msum, o);
  }
  int seq_end = msum - 1;
  int t0 = lab[0], tl = lab[seq_end];
  float score = sc + st[t0] + emg[t0] + en[tl];
  if (tid == 0) llh[b] = score - norm;
}

__global__ __launch_bounds__(64) void loss_kernel(const float* __restrict__ llh,
                                                  float* __restrict__ out) {
  float v = llh[threadIdx.x];
#pragma unroll
  for (int o = 32; o >= 1; o >>= 1) v += __shfl_xor(v, o);
  if (threadIdx.x == 0) out[0] = -(v * (1.0f / 64.0f));
}

extern "C" void kernel_launch(void* const* d_in, const int* in_sizes, int n_in,
                              void* d_out, int out_size, void* d_ws, size_t ws_size,
                              hipStream_t stream) {
  const float* hidden = (const float*)d_in[0];
  const int* amask = (const int*)d_in[1];
  const int* labels = (const int*)d_in[2];
  const float* fc_w = (const float*)d_in[3];
  const float* fc_b = (const float*)d_in[4];
  const float* st = (const float*)d_in[5];
  const float* en = (const float*)d_in[6];
  const float* tr = (const float*)d_in[7];

  float* emws = (float*)d_ws;                          // 655360 floats
  float* llh = emws + (size_t)BB * TT * CC;            // 64
  short* wfrag = (short*)(llh + 64);                   // 24576 shorts
  float* amw = (float*)(wfrag + 24576);                // 1280
  float* bmw = amw + BB * CC;
  float* avw = bmw + BB * CC;
  float* bvw = avw + BB * CC;
  unsigned char* bpws = (unsigned char*)(bvw + BB * CC);  // 327680 B (16B aligned)
  unsigned char* fpws = bpws + (size_t)BB * MID * CC;     // 327680 B
  float* out = (float*)d_out;

  packw_kernel<<<(2 * 24 * 64) / 256, 256, 0, stream>>>(fc_w, wfrag);
  emissions_kernel<<<(BB * TT) / 64, 256, 0, stream>>>(hidden, wfrag, fc_b, emws);
  crf_half_kernel<<<4 * BB, 64, 0, stream>>>(emws, amask, st, en, tr,
                                             amw, bmw, avw, bvw, bpws, fpws);
  finish_kernel<<<BB, 64, 0, stream>>>(emws, amask, labels, st, en, tr,
                                       amw, bmw, avw, bvw, bpws, fpws, llh, out);
  loss_kernel<<<1, 64, 0, stream>>>(llh, out);
}